// Round 18
// baseline (300.728 us; speedup 1.0000x reference)
//
#include <hip/hip_runtime.h>
#include <hip/hip_bf16.h>
#include <stdint.h>

typedef __attribute__((ext_vector_type(4))) float f32x4;
typedef __attribute__((ext_vector_type(8))) short s16x8;

__device__ __forceinline__ short f2bf(float f) {
  union { float f; uint32_t u; } v; v.f = f;
  uint32_t r = v.u + 0x7FFFu + ((v.u >> 16) & 1u);
  return (short)(r >> 16);
}
__device__ __forceinline__ uint32_t pack2bf(float a, float b) {
  return (uint32_t)(uint16_t)f2bf(a) | ((uint32_t)(uint16_t)f2bf(b) << 16);
}

__device__ __forceinline__ void async16(const void* g, void* l) {
  __builtin_amdgcn_global_load_lds(
      (const __attribute__((address_space(1))) void*)g,
      (__attribute__((address_space(3))) void*)l, 16, 0, 0);
}

// ---- transpose+cast body: out[n][k] = bf16(in[k][n]), 64x64 tile ----
__device__ __forceinline__ void transpose_tile(const float* __restrict__ in,
                                               short* __restrict__ out,
                                               int K, int N, int bx, int by, int t) {
  __shared__ float tile[64][65];
  const int tx = t & 63, ty = t >> 6;
#pragma unroll
  for (int r = ty; r < 64; r += 4)
    tile[r][tx] = in[(size_t)(by * 64 + r) * N + bx * 64 + tx];
  __syncthreads();
#pragma unroll
  for (int r = ty; r < 64; r += 4)
    out[(size_t)(bx * 64 + r) * K + by * 64 + tx] = f2bf(tile[tx][r]);
}

// ---- merged prep: blocks [0,16384) cast x; [16384,16576) qkv_w^T; rest proj_w^T ----
__global__ __launch_bounds__(256) void k_prep(const float* __restrict__ x,
                                              short* __restrict__ xbf,
                                              const float* __restrict__ qkv_w,
                                              short* __restrict__ wT,
                                              const float* __restrict__ proj_w,
                                              short* __restrict__ projT) {
  const int bid = blockIdx.x, t = threadIdx.x;
  if (bid < 16384) {
    int i = bid * 256 + t;
    const float4* p = (const float4*)x + (size_t)i * 2;
    float4 a = p[0], b = p[1];
    s16x8 o;
    o[0] = f2bf(a.x); o[1] = f2bf(a.y); o[2] = f2bf(a.z); o[3] = f2bf(a.w);
    o[4] = f2bf(b.x); o[5] = f2bf(b.y); o[6] = f2bf(b.z); o[7] = f2bf(b.w);
    ((s16x8*)xbf)[i] = o;
  } else if (bid < 16384 + 192) {
    int idx = bid - 16384;
    transpose_tile(qkv_w, wT, 512, 1536, idx % 24, idx / 24, t);
  } else {
    int idx = bid - 16384 - 192;
    transpose_tile(proj_w, projT, 512, 512, idx % 8, idx / 8, t);
  }
}

// ===== persistent 256x256 bf16 GEMM — balanced phases + within-tile read-ahead =====
// r18 change vs r17: each phase reads the NEXT phase's fragments before its own
// MFMA cluster; compiler inserts exact counted lgkmcnt (m97 behavior) so the
// just-issued reads overlap the MFMAs. One barrier per phase (4/K-tile), placed
// at phase START so ph3's vmcnt(4) still precedes the tile-publication barrier.
// Reads/phase: 12/8/4/0. Frag regs afX/afY/bfrX/bfrY = 64 VGPR (fits: 48 fit in
// r11 with same addressing). Within-tile reads need NO publication barrier
// (tile data landed at prev ph3 vmcnt(4)+barrier). WAR: B(s+2) overwrites the
// current B-half AFTER all current B-reads (ph0/ph1) — margin >= proven r17.
// Accumulation order identical to r17 (ks0 ai0-7, then ks1 ai0-7).
#define TILE_SH 16384  // 256*64 shorts per tile

template <int OUTMODE, int NBN, int KK>
__global__ __launch_bounds__(512, 2) void k_gemm256p(const short* __restrict__ A,
                                                     const short* __restrict__ Bw,
                                                     const float* __restrict__ bias,
                                                     void* __restrict__ C,
                                                     int N, int nrounds) {
  __shared__ short lds[2 * 2 * TILE_SH];  // 128 KiB
  const int t = threadIdx.x;
  const int w = t >> 6, l = t & 63;
  const int wm = w >> 2, wn = w & 3;
  const int swz = (((int)blockIdx.x & 7) << 5) + ((int)blockIdx.x >> 3);

  const int NT = KK >> 6;  // 8
  const int NS = nrounds * NT;

  auto stage = [&](const short* __restrict__ G, int row0, int kt, short* dst) {
#pragma unroll
    for (int L = 0; L < 2; ++L) {
      int cw = L * 512 + (t & ~63);
      int c = cw + l;
      int r = c >> 3, s = c & 7;
      async16(G + (size_t)(row0 + r) * KK + kt + ((s ^ (r & 7)) << 3), dst + cw * 8);
    }
  };
  auto issueA = [&](int step, int bmv, int hf) {
    int kt = step & 7;
    stage(A, bmv * 256 + hf * 128, kt * 64, lds + (kt & 1) * 32768 + hf * 8192);
  };
  auto issueB = [&](int step, int bnv, int hf) {
    int kt = step & 7;
    stage(Bw, bnv * 256 + hf * 128, kt * 64, lds + (kt & 1) * 32768 + TILE_SH + hf * 8192);
  };

  const int g = l >> 4, v = l & 7;
  int ofsA[2], ofsB[2];
#pragma unroll
  for (int ks = 0; ks < 2; ++ks) {
    ofsA[ks] = (wm * 128 + (l & 15)) * 64 + (((ks * 4 + g) ^ v) << 3);
    ofsB[ks] = (wn * 64 + (l & 15)) * 64 + (((ks * 4 + g) ^ v) << 3);
  }

  f32x4 acc[8][4] = {};
  s16x8 afX[4], afY[4], bfrX[4], bfrY[4];

#define RDA4(D, BASE, KS, AI0)                                        \
  D[0] = *(const s16x8*)((BASE) + ofsA[KS] + ((AI0) + 0) * 1024);     \
  D[1] = *(const s16x8*)((BASE) + ofsA[KS] + ((AI0) + 1) * 1024);     \
  D[2] = *(const s16x8*)((BASE) + ofsA[KS] + ((AI0) + 2) * 1024);     \
  D[3] = *(const s16x8*)((BASE) + ofsA[KS] + ((AI0) + 3) * 1024);

#define RDB4(D, BASE, KS)                                             \
  D[0] = *(const s16x8*)((BASE) + ofsB[KS] + 0 * 1024);               \
  D[1] = *(const s16x8*)((BASE) + ofsB[KS] + 1 * 1024);               \
  D[2] = *(const s16x8*)((BASE) + ofsB[KS] + 2 * 1024);               \
  D[3] = *(const s16x8*)((BASE) + ofsB[KS] + 3 * 1024);

#define MF16(AF, BF, AI0)                                                                                      \
  __builtin_amdgcn_s_setprio(1);                                                                               \
  _Pragma("unroll")                                                                                            \
  for (int nj = 0; nj < 4; ++nj) {                                                                             \
    acc[(AI0) + 0][nj] = __builtin_amdgcn_mfma_f32_16x16x32_bf16(AF[0], BF[nj], acc[(AI0) + 0][nj], 0, 0, 0);  \
    acc[(AI0) + 1][nj] = __builtin_amdgcn_mfma_f32_16x16x32_bf16(AF[1], BF[nj], acc[(AI0) + 1][nj], 0, 0, 0);  \
    acc[(AI0) + 2][nj] = __builtin_amdgcn_mfma_f32_16x16x32_bf16(AF[2], BF[nj], acc[(AI0) + 2][nj], 0, 0, 0);  \
    acc[(AI0) + 3][nj] = __builtin_amdgcn_mfma_f32_16x16x32_bf16(AF[3], BF[nj], acc[(AI0) + 3][nj], 0, 0, 0);  \
  }                                                                                                            \
  __builtin_amdgcn_s_setprio(0);

  // prologue: B(0), A(0), B(1); vmcnt(4) -> A(0),B(0) landed (B(1) in flight)
  {
    const int bm0 = swz / NBN, bn0 = swz % NBN;
    issueB(0, bn0, 0); issueB(0, bn0, 1);
    issueA(0, bm0, 0); issueA(0, bm0, 1);
    issueB(1, bn0, 0); issueB(1, bn0, 1);
  }
  asm volatile("s_waitcnt vmcnt(4)" ::: "memory");

  for (int j = 0; j < nrounds; ++j) {
    const int tauc = swz + (j << 8);
    const int bmc = tauc / NBN, bnc = tauc % NBN;
    for (int T = 0; T < NT; ++T) {
      const int s = (j << 3) + T;
      const int s1 = s + 1, s2 = s + 2;
      const int tau1 = swz + ((s1 >> 3) << 8);
      const int tau2 = swz + ((s2 >> 3) << 8);
      const int bm1 = tau1 / NBN;
      const int bn2 = tau2 % NBN;
      const short* Ab = lds + (T & 1) * 32768;
      const short* Bb = Ab + TILE_SH;

      // ph0: publication barrier; read set1 (ks0: 4B+4A-lo) + set2 (ks0: 4A-hi);
      //      stage A(s+1)h0; MFMA set1 (set2 reads fly underneath)
      __builtin_amdgcn_s_barrier();
      RDB4(bfrX, Bb, 0);
      RDA4(afX, Ab, 0, 0);
      RDA4(afY, Ab, 0, 4);
      if (s1 < NS) issueA(s1, bm1, 0);
      MF16(afX, bfrX, 0);

      // ph1: read set3 (ks1: 4B+4A-lo); stage A(s+1)h1; MFMA set2
      __builtin_amdgcn_s_barrier();
      RDB4(bfrY, Bb, 1);
      RDA4(afX, Ab, 1, 0);
      if (s1 < NS) issueA(s1, bm1, 1);
      MF16(afY, bfrX, 4);

      // ph2: read set4 (ks1: 4A-hi); stage B(s+2)h0; MFMA set3
      __builtin_amdgcn_s_barrier();
      RDA4(afY, Ab, 1, 4);
      if (s2 < NS) issueB(s2, bn2, 0);
      MF16(afX, bfrY, 0);

      // ph3: no reads; stage B(s+2)h1; MFMA set4; tail vmcnt (publication,
      //      sealed by next phase's opening barrier)
      __builtin_amdgcn_s_barrier();
      if (s2 < NS) issueB(s2, bn2, 1);
      MF16(afY, bfrY, 4);
      if (s2 < NS) { asm volatile("s_waitcnt vmcnt(4)" ::: "memory"); }
      else if (s1 < NS) { asm volatile("s_waitcnt vmcnt(0)" ::: "memory"); }
    }

    // epilogue tile j (global stores only; next tile's ph0 barrier follows)
#pragma unroll
    for (int ai = 0; ai < 8; ++ai)
#pragma unroll
      for (int nj = 0; nj < 4; ++nj) {
        int col = bnc * 256 + wn * 64 + nj * 16 + (l & 15);
        float bv = bias[col];
#pragma unroll
        for (int r = 0; r < 4; ++r) {
          int row = bmc * 256 + wm * 128 + ai * 16 + (l >> 4) * 4 + r;
          float vv = acc[ai][nj][r] + bv;
          if (OUTMODE == 1) {
            ((float*)C)[(size_t)row * N + col] = vv;
          } else if (OUTMODE == 0) {
            ((short*)C)[(size_t)row * N + col] = f2bf(vv);
          } else {
            int bb = row >> 6, nn = row & 63;
            int sel = col >> 9, hh = (col >> 5) & 15, dd = col & 31;
            ((short*)C)[(((size_t)(bb * 48 + hh * 3 + sel)) << 11) + (nn << 5) + dd] = f2bf(vv);
          }
        }
      }
#pragma unroll
    for (int ai = 0; ai < 8; ++ai)
#pragma unroll
      for (int nj = 0; nj < 4; ++nj)
        acc[ai][nj] = (f32x4){0.f, 0.f, 0.f, 0.f};
  }
#undef MF16
#undef RDA4
#undef RDB4
}

// ============== fused window attention (r16 proven) ==============
__global__ __launch_bounds__(256) void k_attn(const short* __restrict__ qkv2,
                                              const float* __restrict__ mask,
                                              const float* __restrict__ bias_table,
                                              short* __restrict__ Y) {
  __shared__ __align__(16) float mask_lds[64 * 64];   // [n][m ^ ((n&7)<<2)]
  __shared__ float bias_lds[4][128];
  __shared__ short p_lds[4][64][72];
  __shared__ short v_lds[4][64][40];

  const int t = threadIdx.x, wv = t >> 6, ln = t & 63;
  const int b = blockIdx.x;
  const int h = blockIdx.y * 4 + wv;
  const int hi = ln >> 4, lo = ln & 15;

  const float4* mk = (const float4*)(mask + (size_t)(b & 63) * 4096);
#pragma unroll
  for (int u = 0; u < 4; ++u) {
    int idx = t + 256 * u;
    int row = idx >> 4, c4 = (idx & 15) * 4;
    *(float4*)&mask_lds[row * 64 + (c4 ^ ((row & 7) << 2))] = mk[idx];
  }
  for (int u = ln; u < 127; u += 64) bias_lds[wv][u] = bias_table[u * 16 + h];

  const short* base = qkv2 + ((size_t)(b * 16 + h)) * 3 * 2048;
  const short* vg = base + 4096;
#pragma unroll
  for (int u = 0; u < 4; ++u) {
    int row = u * 16 + (ln >> 2), c8 = (ln & 3) * 8;
    *(s16x8*)&v_lds[wv][row][c8] = *(const s16x8*)(vg + row * 32 + c8);
  }
  __syncthreads();

  s16x8 qf[4], kf[4];
#pragma unroll
  for (int i = 0; i < 4; ++i) {
    qf[i] = *(const s16x8*)(base + (16 * i + lo) * 32 + hi * 8);
    kf[i] = *(const s16x8*)(base + 2048 + (16 * i + lo) * 32 + hi * 8);
  }
  f32x4 s2[4][4] = {};
#pragma unroll
  for (int j = 0; j < 4; ++j)
#pragma unroll
    for (int i = 0; i < 4; ++i)
      s2[j][i] = __builtin_amdgcn_mfma_f32_16x16x32_bf16(kf[j], qf[i], s2[j][i], 0, 0, 0);

  const float scale = 0.17677669529663687f;
#pragma unroll
  for (int i = 0; i < 4; ++i) {
    const int n = 16 * i + lo;
    const int msw = (n & 7) << 2;
    float x[16];
    float vmax = -1e30f;
#pragma unroll
    for (int j = 0; j < 4; ++j) {
      float4 mrow = *(const float4*)&mask_lds[n * 64 + ((16 * j + 4 * hi) ^ msw)];
#pragma unroll
      for (int r = 0; r < 4; ++r) {
        int m = 16 * j + 4 * hi + r;
        float xx = s2[j][i][r] * scale + bias_lds[wv][n - m + 63] + (&mrow.x)[r];
        x[j * 4 + r] = xx;
        vmax = fmaxf(vmax, xx);
      }
    }
    vmax = fmaxf(vmax, __shfl_xor(vmax, 16, 64));
    vmax = fmaxf(vmax, __shfl_xor(vmax, 32, 64));
    float sum = 0.f;
#pragma unroll
    for (int u = 0; u < 16; ++u) {
      x[u] = __expf(x[u] - vmax);
      sum += x[u];
    }
    sum += __shfl_xor(sum, 16, 64);
    sum += __shfl_xor(sum, 32, 64);
    float rsv = 1.0f / sum;
#pragma unroll
    for (int j = 0; j < 4; ++j)
#pragma unroll
      for (int rp = 0; rp < 2; ++rp)
        *(uint32_t*)&p_lds[wv][n][16 * j + 4 * hi + rp * 2] =
            pack2bf(x[j * 4 + rp * 2] * rsv, x[j * 4 + rp * 2 + 1] * rsv);
  }

  f32x4 o2[2][4] = {};
#pragma unroll
  for (int kk = 0; kk < 2; ++kk) {
    s16x8 pa[4];
#pragma unroll
    for (int i2 = 0; i2 < 4; ++i2)
      pa[i2] = *(const s16x8*)&p_lds[wv][16 * i2 + lo][kk * 32 + hi * 8];
#pragma unroll
    for (int j2 = 0; j2 < 2; ++j2) {
      s16x8 vf;
#pragma unroll
      for (int jj = 0; jj < 8; ++jj)
        vf[jj] = v_lds[wv][kk * 32 + hi * 8 + jj][16 * j2 + lo];
#pragma unroll
      for (int i2 = 0; i2 < 4; ++i2)
        o2[j2][i2] = __builtin_amdgcn_mfma_f32_16x16x32_bf16(vf, pa[i2], o2[j2][i2], 0, 0, 0);
    }
  }

  const int rr = h * 64 + (b >> 4);
#pragma unroll
  for (int i2 = 0; i2 < 4; ++i2) {
    int ss = (b & 15) * 4 + i2;
    short* yr = Y + ((size_t)rr * 64 + ss) * 512 + lo * 32 + 4 * hi;
#pragma unroll
    for (int j2 = 0; j2 < 2; ++j2) {
      uint2 pk;
      pk.x = pack2bf(o2[j2][i2][0], o2[j2][i2][1]);
      pk.y = pack2bf(o2[j2][i2][2], o2[j2][i2][3]);
      *(uint2*)(yr + 16 * j2) = pk;
    }
  }
}

extern "C" void kernel_launch(void* const* d_in, const int* in_sizes, int n_in,
                              void* d_out, int out_size, void* d_ws, size_t ws_size,
                              hipStream_t stream) {
  const float* x      = (const float*)d_in[0];
  const float* mask   = (const float*)d_in[1];
  const float* qkv_w  = (const float*)d_in[2];
  const float* qkv_b  = (const float*)d_in[3];
  const float* proj_w = (const float*)d_in[4];
  const float* proj_b = (const float*)d_in[5];
  const float* btab   = (const float*)d_in[6];
  float* out = (float*)d_out;

  char* w = (char*)d_ws;
  short* qkv_ws = (short*)w;                                             // 192 MiB
  short* xbf    = (short*)(w + (size_t)65536 * 1536 * 2);                // 64 MiB
  short* Y      = xbf;                                                   // reuse after GEMM1
  short* wT     = (short*)(w + (size_t)65536 * 1536 * 2 + (size_t)65536 * 512 * 2);
  short* projT  = wT + 1536 * 512;

  k_prep<<<16384 + 192 + 64, 256, 0, stream>>>(x, xbf, qkv_w, wT, proj_w, projT);
  k_gemm256p<2, 6, 512><<<256, 512, 0, stream>>>(xbf, wT, qkv_b, qkv_ws, 1536, 6);
  k_attn<<<dim3(1024, 4), 256, 0, stream>>>(qkv_ws, mask, btab, Y);
  k_gemm256p<1, 2, 512><<<256, 512, 0, stream>>>(Y, projT, proj_b, out, 512, 2);
}

// Round 19
// 273.575 us; speedup vs baseline: 1.0993x; 1.0993x over previous
//
#include <hip/hip_runtime.h>
#include <hip/hip_bf16.h>
#include <stdint.h>

typedef __attribute__((ext_vector_type(4))) float f32x4;
typedef __attribute__((ext_vector_type(8))) short s16x8;

__device__ __forceinline__ short f2bf(float f) {
  union { float f; uint32_t u; } v; v.f = f;
  uint32_t r = v.u + 0x7FFFu + ((v.u >> 16) & 1u);
  return (short)(r >> 16);
}
__device__ __forceinline__ uint32_t pack2bf(float a, float b) {
  return (uint32_t)(uint16_t)f2bf(a) | ((uint32_t)(uint16_t)f2bf(b) << 16);
}

__device__ __forceinline__ void async16(const void* g, void* l) {
  __builtin_amdgcn_global_load_lds(
      (const __attribute__((address_space(1))) void*)g,
      (__attribute__((address_space(3))) void*)l, 16, 0, 0);
}

// ---- transpose+cast body: out[n][k] = bf16(in[k][n]), 64x64 tile ----
__device__ __forceinline__ void transpose_tile(const float* __restrict__ in,
                                               short* __restrict__ out,
                                               int K, int N, int bx, int by, int t) {
  __shared__ float tile[64][65];
  const int tx = t & 63, ty = t >> 6;
#pragma unroll
  for (int r = ty; r < 64; r += 4)
    tile[r][tx] = in[(size_t)(by * 64 + r) * N + bx * 64 + tx];
  __syncthreads();
#pragma unroll
  for (int r = ty; r < 64; r += 4)
    out[(size_t)(bx * 64 + r) * K + by * 64 + tx] = f2bf(tile[tx][r]);
}

// ---- merged prep: blocks [0,16384) cast x; [16384,16576) qkv_w^T; rest proj_w^T ----
__global__ __launch_bounds__(256) void k_prep(const float* __restrict__ x,
                                              short* __restrict__ xbf,
                                              const float* __restrict__ qkv_w,
                                              short* __restrict__ wT,
                                              const float* __restrict__ proj_w,
                                              short* __restrict__ projT) {
  const int bid = blockIdx.x, t = threadIdx.x;
  if (bid < 16384) {
    int i = bid * 256 + t;
    const float4* p = (const float4*)x + (size_t)i * 2;
    float4 a = p[0], b = p[1];
    s16x8 o;
    o[0] = f2bf(a.x); o[1] = f2bf(a.y); o[2] = f2bf(a.z); o[3] = f2bf(a.w);
    o[4] = f2bf(b.x); o[5] = f2bf(b.y); o[6] = f2bf(b.z); o[7] = f2bf(b.w);
    ((s16x8*)xbf)[i] = o;
  } else if (bid < 16384 + 192) {
    int idx = bid - 16384;
    transpose_tile(qkv_w, wT, 512, 1536, idx % 24, idx / 24, t);
  } else {
    int idx = bid - 16384 - 192;
    transpose_tile(proj_w, projT, 512, 512, idx % 8, idx / 8, t);
  }
}

// ===== persistent 256x256 8-phase bf16 GEMM — balanced-read phases (r17) =====
// Phases partition by (ai-half x ks): ds_reads 8/4/8/4 per phase (LDS/MFMA
// pipes balanced). Live frag regs 32. PROVEN at 126 us; r18's read-ahead
// variant (64 frag regs) spilled — 512-thr block -> >=2 waves/EU -> <=256
// regs/wave is a hard wall. Do not add live state.
#define TILE_SH 16384  // 256*64 shorts per tile

template <int OUTMODE, int NBN, int KK>
__global__ __launch_bounds__(512, 2) void k_gemm256p(const short* __restrict__ A,
                                                     const short* __restrict__ Bw,
                                                     const float* __restrict__ bias,
                                                     void* __restrict__ C,
                                                     int N, int nrounds) {
  __shared__ short lds[2 * 2 * TILE_SH];  // 128 KiB
  const int t = threadIdx.x;
  const int w = t >> 6, l = t & 63;
  const int wm = w >> 2, wn = w & 3;
  const int swz = (((int)blockIdx.x & 7) << 5) + ((int)blockIdx.x >> 3);

  const int NT = KK >> 6;  // 8
  const int NS = nrounds * NT;

  auto stage = [&](const short* __restrict__ G, int row0, int kt, short* dst) {
#pragma unroll
    for (int L = 0; L < 2; ++L) {
      int cw = L * 512 + (t & ~63);
      int c = cw + l;
      int r = c >> 3, s = c & 7;
      async16(G + (size_t)(row0 + r) * KK + kt + ((s ^ (r & 7)) << 3), dst + cw * 8);
    }
  };
  auto issueA = [&](int step, int bmv, int hf) {
    int kt = step & 7;
    stage(A, bmv * 256 + hf * 128, kt * 64, lds + (kt & 1) * 32768 + hf * 8192);
  };
  auto issueB = [&](int step, int bnv, int hf) {
    int kt = step & 7;
    stage(Bw, bnv * 256 + hf * 128, kt * 64, lds + (kt & 1) * 32768 + TILE_SH + hf * 8192);
  };

  const int g = l >> 4, v = l & 7;
  int ofsA[2], ofsB[2];
#pragma unroll
  for (int ks = 0; ks < 2; ++ks) {
    ofsA[ks] = (wm * 128 + (l & 15)) * 64 + (((ks * 4 + g) ^ v) << 3);
    ofsB[ks] = (wn * 64 + (l & 15)) * 64 + (((ks * 4 + g) ^ v) << 3);
  }

  f32x4 acc[8][4] = {};
  s16x8 af[4], bfr[4];

#define RDA4(BASE, KS, AI0)                                           \
  af[0] = *(const s16x8*)((BASE) + ofsA[KS] + ((AI0) + 0) * 1024);    \
  af[1] = *(const s16x8*)((BASE) + ofsA[KS] + ((AI0) + 1) * 1024);    \
  af[2] = *(const s16x8*)((BASE) + ofsA[KS] + ((AI0) + 2) * 1024);    \
  af[3] = *(const s16x8*)((BASE) + ofsA[KS] + ((AI0) + 3) * 1024);

#define RDB4(BASE, KS)                                                \
  bfr[0] = *(const s16x8*)((BASE) + ofsB[KS] + 0 * 1024);             \
  bfr[1] = *(const s16x8*)((BASE) + ofsB[KS] + 1 * 1024);             \
  bfr[2] = *(const s16x8*)((BASE) + ofsB[KS] + 2 * 1024);             \
  bfr[3] = *(const s16x8*)((BASE) + ofsB[KS] + 3 * 1024);

#define MF16(AI0)                                                                                              \
  __builtin_amdgcn_s_setprio(1);                                                                               \
  _Pragma("unroll")                                                                                            \
  for (int nj = 0; nj < 4; ++nj) {                                                                             \
    acc[(AI0) + 0][nj] = __builtin_amdgcn_mfma_f32_16x16x32_bf16(af[0], bfr[nj], acc[(AI0) + 0][nj], 0, 0, 0); \
    acc[(AI0) + 1][nj] = __builtin_amdgcn_mfma_f32_16x16x32_bf16(af[1], bfr[nj], acc[(AI0) + 1][nj], 0, 0, 0); \
    acc[(AI0) + 2][nj] = __builtin_amdgcn_mfma_f32_16x16x32_bf16(af[2], bfr[nj], acc[(AI0) + 2][nj], 0, 0, 0); \
    acc[(AI0) + 3][nj] = __builtin_amdgcn_mfma_f32_16x16x32_bf16(af[3], bfr[nj], acc[(AI0) + 3][nj], 0, 0, 0); \
  }                                                                                                            \
  __builtin_amdgcn_s_setprio(0);

#define PHASE(RD_STMT, STAGE_STMT, AI0, TAIL_STMT)      \
  {                                                     \
    RD_STMT;                                            \
    STAGE_STMT;                                         \
    __builtin_amdgcn_s_barrier();                       \
    asm volatile("s_waitcnt lgkmcnt(0)" ::: "memory");  \
    MF16(AI0);                                          \
    TAIL_STMT;                                          \
    __builtin_amdgcn_s_barrier();                       \
  }

  {
    const int bm0 = swz / NBN, bn0 = swz % NBN;
    issueB(0, bn0, 0); issueB(0, bn0, 1);
    issueA(0, bm0, 0); issueA(0, bm0, 1);
    issueB(1, bn0, 0); issueB(1, bn0, 1);
  }
  asm volatile("s_waitcnt vmcnt(4)" ::: "memory");
  __builtin_amdgcn_s_barrier();

  for (int j = 0; j < nrounds; ++j) {
    const int tauc = swz + (j << 8);
    const int bmc = tauc / NBN, bnc = tauc % NBN;
    for (int T = 0; T < NT; ++T) {
      const int s = (j << 3) + T;
      const int s1 = s + 1, s2 = s + 2;
      const int tau1 = swz + ((s1 >> 3) << 8);
      const int tau2 = swz + ((s2 >> 3) << 8);
      const int bm1 = tau1 / NBN;
      const int bn2 = tau2 % NBN;
      const short* Ab = lds + (T & 1) * 32768;
      const short* Bb = Ab + TILE_SH;

      // ph0: ai0-3 @ks0 (reads 4A+4B); stage A(s+1)h0
      PHASE(RDB4(Bb, 0); RDA4(Ab, 0, 0), if (s1 < NS) issueA(s1, bm1, 0), 0, );
      // ph1: ai4-7 @ks0 (4A); stage A(s+1)h1
      PHASE(RDA4(Ab, 0, 4), if (s1 < NS) issueA(s1, bm1, 1), 4, );
      // ph2: ai0-3 @ks1 (4A+4B); stage B(s+2)h0
      PHASE(RDB4(Bb, 1); RDA4(Ab, 1, 0), if (s2 < NS) issueB(s2, bn2, 0), 0, );
      // ph3: ai4-7 @ks1 (4A); stage B(s+2)h1; tail vmcnt
      PHASE(RDA4(Ab, 1, 4), if (s2 < NS) issueB(s2, bn2, 1), 4,
            if (s2 < NS) { asm volatile("s_waitcnt vmcnt(4)" ::: "memory"); }
            else if (s1 < NS) { asm volatile("s_waitcnt vmcnt(0)" ::: "memory"); });
    }

    // epilogue tile j: stores overlap next tile's K-loop
#pragma unroll
    for (int ai = 0; ai < 8; ++ai)
#pragma unroll
      for (int nj = 0; nj < 4; ++nj) {
        int col = bnc * 256 + wn * 64 + nj * 16 + (l & 15);
        float bv = bias[col];
#pragma unroll
        for (int r = 0; r < 4; ++r) {
          int row = bmc * 256 + wm * 128 + ai * 16 + (l >> 4) * 4 + r;
          float vv = acc[ai][nj][r] + bv;
          if (OUTMODE == 1) {
            ((float*)C)[(size_t)row * N + col] = vv;
          } else if (OUTMODE == 0) {
            ((short*)C)[(size_t)row * N + col] = f2bf(vv);
          } else {
            int bb = row >> 6, nn = row & 63;
            int sel = col >> 9, hh = (col >> 5) & 15, dd = col & 31;
            ((short*)C)[(((size_t)(bb * 48 + hh * 3 + sel)) << 11) + (nn << 5) + dd] = f2bf(vv);
          }
        }
      }
#pragma unroll
    for (int ai = 0; ai < 8; ++ai)
#pragma unroll
      for (int nj = 0; nj < 4; ++nj)
        acc[ai][nj] = (f32x4){0.f, 0.f, 0.f, 0.f};
  }
#undef PHASE
#undef MF16
#undef RDA4
#undef RDB4
}

// ============== fused window attention (r16 proven) ==============
__global__ __launch_bounds__(256) void k_attn(const short* __restrict__ qkv2,
                                              const float* __restrict__ mask,
                                              const float* __restrict__ bias_table,
                                              short* __restrict__ Y) {
  __shared__ __align__(16) float mask_lds[64 * 64];   // [n][m ^ ((n&7)<<2)]
  __shared__ float bias_lds[4][128];
  __shared__ short p_lds[4][64][72];
  __shared__ short v_lds[4][64][40];

  const int t = threadIdx.x, wv = t >> 6, ln = t & 63;
  const int b = blockIdx.x;
  const int h = blockIdx.y * 4 + wv;
  const int hi = ln >> 4, lo = ln & 15;

  const float4* mk = (const float4*)(mask + (size_t)(b & 63) * 4096);
#pragma unroll
  for (int u = 0; u < 4; ++u) {
    int idx = t + 256 * u;
    int row = idx >> 4, c4 = (idx & 15) * 4;
    *(float4*)&mask_lds[row * 64 + (c4 ^ ((row & 7) << 2))] = mk[idx];
  }
  for (int u = ln; u < 127; u += 64) bias_lds[wv][u] = bias_table[u * 16 + h];

  const short* base = qkv2 + ((size_t)(b * 16 + h)) * 3 * 2048;
  const short* vg = base + 4096;
#pragma unroll
  for (int u = 0; u < 4; ++u) {
    int row = u * 16 + (ln >> 2), c8 = (ln & 3) * 8;
    *(s16x8*)&v_lds[wv][row][c8] = *(const s16x8*)(vg + row * 32 + c8);
  }
  __syncthreads();

  s16x8 qf[4], kf[4];
#pragma unroll
  for (int i = 0; i < 4; ++i) {
    qf[i] = *(const s16x8*)(base + (16 * i + lo) * 32 + hi * 8);
    kf[i] = *(const s16x8*)(base + 2048 + (16 * i + lo) * 32 + hi * 8);
  }
  f32x4 s2[4][4] = {};
#pragma unroll
  for (int j = 0; j < 4; ++j)
#pragma unroll
    for (int i = 0; i < 4; ++i)
      s2[j][i] = __builtin_amdgcn_mfma_f32_16x16x32_bf16(kf[j], qf[i], s2[j][i], 0, 0, 0);

  const float scale = 0.17677669529663687f;
#pragma unroll
  for (int i = 0; i < 4; ++i) {
    const int n = 16 * i + lo;
    const int msw = (n & 7) << 2;
    float x[16];
    float vmax = -1e30f;
#pragma unroll
    for (int j = 0; j < 4; ++j) {
      float4 mrow = *(const float4*)&mask_lds[n * 64 + ((16 * j + 4 * hi) ^ msw)];
#pragma unroll
      for (int r = 0; r < 4; ++r) {
        int m = 16 * j + 4 * hi + r;
        float xx = s2[j][i][r] * scale + bias_lds[wv][n - m + 63] + (&mrow.x)[r];
        x[j * 4 + r] = xx;
        vmax = fmaxf(vmax, xx);
      }
    }
    vmax = fmaxf(vmax, __shfl_xor(vmax, 16, 64));
    vmax = fmaxf(vmax, __shfl_xor(vmax, 32, 64));
    float sum = 0.f;
#pragma unroll
    for (int u = 0; u < 16; ++u) {
      x[u] = __expf(x[u] - vmax);
      sum += x[u];
    }
    sum += __shfl_xor(sum, 16, 64);
    sum += __shfl_xor(sum, 32, 64);
    float rsv = 1.0f / sum;
#pragma unroll
    for (int j = 0; j < 4; ++j)
#pragma unroll
      for (int rp = 0; rp < 2; ++rp)
        *(uint32_t*)&p_lds[wv][n][16 * j + 4 * hi + rp * 2] =
            pack2bf(x[j * 4 + rp * 2] * rsv, x[j * 4 + rp * 2 + 1] * rsv);
  }

  f32x4 o2[2][4] = {};
#pragma unroll
  for (int kk = 0; kk < 2; ++kk) {
    s16x8 pa[4];
#pragma unroll
    for (int i2 = 0; i2 < 4; ++i2)
      pa[i2] = *(const s16x8*)&p_lds[wv][16 * i2 + lo][kk * 32 + hi * 8];
#pragma unroll
    for (int j2 = 0; j2 < 2; ++j2) {
      s16x8 vf;
#pragma unroll
      for (int jj = 0; jj < 8; ++jj)
        vf[jj] = v_lds[wv][kk * 32 + hi * 8 + jj][16 * j2 + lo];
#pragma unroll
      for (int i2 = 0; i2 < 4; ++i2)
        o2[j2][i2] = __builtin_amdgcn_mfma_f32_16x16x32_bf16(vf, pa[i2], o2[j2][i2], 0, 0, 0);
    }
  }

  const int rr = h * 64 + (b >> 4);
#pragma unroll
  for (int i2 = 0; i2 < 4; ++i2) {
    int ss = (b & 15) * 4 + i2;
    short* yr = Y + ((size_t)rr * 64 + ss) * 512 + lo * 32 + 4 * hi;
#pragma unroll
    for (int j2 = 0; j2 < 2; ++j2) {
      uint2 pk;
      pk.x = pack2bf(o2[j2][i2][0], o2[j2][i2][1]);
      pk.y = pack2bf(o2[j2][i2][2], o2[j2][i2][3]);
      *(uint2*)(yr + 16 * j2) = pk;
    }
  }
}

extern "C" void kernel_launch(void* const* d_in, const int* in_sizes, int n_in,
                              void* d_out, int out_size, void* d_ws, size_t ws_size,
                              hipStream_t stream) {
  const float* x      = (const float*)d_in[0];
  const float* mask   = (const float*)d_in[1];
  const float* qkv_w  = (const float*)d_in[2];
  const float* qkv_b  = (const float*)d_in[3];
  const float* proj_w = (const float*)d_in[4];
  const float* proj_b = (const float*)d_in[5];
  const float* btab   = (const float*)d_in[6];
  float* out = (float*)d_out;

  char* w = (char*)d_ws;
  short* qkv_ws = (short*)w;                                             // 192 MiB
  short* xbf    = (short*)(w + (size_t)65536 * 1536 * 2);                // 64 MiB
  short* Y      = xbf;                                                   // reuse after GEMM1
  short* wT     = (short*)(w + (size_t)65536 * 1536 * 2 + (size_t)65536 * 512 * 2);
  short* projT  = wT + 1536 * 512;

  k_prep<<<16384 + 192 + 64, 256, 0, stream>>>(x, xbf, qkv_w, wT, proj_w, projT);
  k_gemm256p<2, 6, 512><<<256, 512, 0, stream>>>(xbf, wT, qkv_b, qkv_ws, 1536, 6);
  k_attn<<<dim3(1024, 4), 256, 0, stream>>>(qkv_ws, mask, btab, Y);
  k_gemm256p<1, 2, 512><<<256, 512, 0, stream>>>(Y, projT, proj_b, out, 512, 2);
}